// Round 3
// baseline (8530.914 us; speedup 1.0000x reference)
//
#include <hip/hip_runtime.h>

typedef unsigned short u16;
typedef unsigned int u32;
typedef unsigned long long u64;
typedef short short8 __attribute__((ext_vector_type(8)));
typedef float f32x4 __attribute__((ext_vector_type(4)));

static constexpr int T = 512, B = 128, D = 512, H = 512;

// ---- workspace layout (bytes) ----
static constexpr size_t WS_WPACK = 0;                    // bf16 W blocked: 3,145,728
static constexpr size_t WS_MASK  = 3145728;              // float[512][128]: 262,144
static constexpr size_t WS_HBFA  = WS_MASK + 262144;     // u16[2][8 rg][64 kb][16 row][8]: 262,144
static constexpr size_t WS_FLAGS = WS_HBFA + 262144;     // u32[8 rg][32 cgi][4 wv]: 4,096
static constexpr size_t WS_XPACK = WS_FLAGS + 4096;      // bf16 x A-blocked: 67,108,864

__device__ __forceinline__ u32 f2bf(float f) {
  unsigned b = __float_as_uint(f);
  b = (b + 0x7FFFu + ((b >> 16) & 1u)) >> 16;  // RN-even
  return b & 0xFFFFu;
}

// Pack Wi[512,1536], Wh_rz[512,1024], Wh_n[512,512] (fp32) into bf16 blocked
// B-fragment layout: wpack[cg][kb][n][i] = W[k=kb*8+i][gate g=n>>4, col j=cg*16+(n&15)]
__global__ void pack_w_kernel(const float* __restrict__ Wi,
                              const float* __restrict__ Whrz,
                              const float* __restrict__ Whn,
                              u16* __restrict__ wpack) {
  int c = blockIdx.x * 256 + threadIdx.x;
  if (c >= 32 * 128 * 48) return;
  int n  = c % 48;
  int kb = (c / 48) % 128;
  int cgrp = c / (48 * 128);
  int g = n >> 4, jl = n & 15;
  int j = cgrp * 16 + jl;
  u16 tmp[8] __attribute__((aligned(16)));
#pragma unroll
  for (int i = 0; i < 8; ++i) {
    int k = kb * 8 + i;
    float v;
    if (k < 512) {
      v = Wi[k * 1536 + g * 512 + j];
    } else {
      int kh = k - 512;
      v = (g == 0) ? Whrz[kh * 1024 + j]
        : (g == 1) ? Whrz[kh * 1024 + 512 + j]
                   : Whn[kh * 512 + j];
    }
    tmp[i] = (u16)f2bf(v);
  }
  *reinterpret_cast<uint4*>(wpack + (size_t)c * 8) = *reinterpret_cast<const uint4*>(tmp);
}

// Detect resets dtype, build keep-mask [T][B], init h buf0 in A-layout, zero flags.
__global__ void init_kernel(const void* __restrict__ resets_raw,
                            const float* __restrict__ h0,
                            float* __restrict__ mask,
                            u16* __restrict__ hbfA,
                            u32* __restrict__ flags) {
  __shared__ int s_flags;
  if (threadIdx.x == 0) s_flags = 0;
  __syncthreads();
  const unsigned char* u8 = (const unsigned char*)resets_raw;
  {
    int p = threadIdx.x * 4;
    int f = 0;
    if (u8[p + 1] | u8[p + 2]) f |= 1;
    unsigned char b3 = u8[p + 3];
    if (b3 == 0x3F) f |= 2;
    else if (b3) f |= 1;
    if (f) atomicOr(&s_flags, f);
  }
  __syncthreads();
  int fl = s_flags;
  int idx = blockIdx.x * 256 + threadIdx.x;          // 0..65535
  bool rv;
  if (fl & 2)      rv = ((const float*)resets_raw)[idx] != 0.0f;
  else if (fl & 1) rv = u8[idx] != 0;
  else             rv = ((const int*)resets_raw)[idx] != 0;
  mask[idx] = rv ? 0.0f : 1.0f;
  int b = idx >> 9, j = idx & 511;
  bool r0;
  if (fl & 2)      r0 = ((const float*)resets_raw)[b] != 0.0f;
  else if (fl & 1) r0 = u8[b] != 0;
  else             r0 = ((const int*)resets_raw)[b] != 0;
  float h = r0 ? 0.0f : h0[idx];
  int rg = b >> 4, row = b & 15, kb = j >> 3, i = j & 7;
  hbfA[(((size_t)rg * 64 + kb) * 16 + row) * 8 + i] = (u16)f2bf(h);  // buf 0
  if (blockIdx.x < 4) flags[blockIdx.x * 256 + threadIdx.x] = 0;
}

// Pre-pass: ins fp32 -> bf16 in A-fragment blocked layout xpack[t][rg][kb][row][8].
// LDS transpose so both global read and write are coalesced.
__global__ void convert_x_kernel(const float* __restrict__ ins, u16* __restrict__ xpack) {
  __shared__ u16 s_x[16 * 520];                      // +8 pad kills phase-2 conflicts
  int t = blockIdx.x >> 3, rg = blockIdx.x & 7;
  int tid = threadIdx.x;
#pragma unroll
  for (int p = 0; p < 4; ++p) {
    int row = p * 4 + (tid >> 6);
    int col = (tid & 63) * 8;
    const float* s = ins + ((size_t)t * B + rg * 16 + row) * D + col;
    float4 f0 = *reinterpret_cast<const float4*>(s);
    float4 f1 = *reinterpret_cast<const float4*>(s + 4);
    u16* d = s_x + row * 520 + col;
    d[0]=(u16)f2bf(f0.x); d[1]=(u16)f2bf(f0.y); d[2]=(u16)f2bf(f0.z); d[3]=(u16)f2bf(f0.w);
    d[4]=(u16)f2bf(f1.x); d[5]=(u16)f2bf(f1.y); d[6]=(u16)f2bf(f1.z); d[7]=(u16)f2bf(f1.w);
  }
  __syncthreads();
  u16* dst = xpack + ((size_t)t * 8 + rg) * 8192;
#pragma unroll
  for (int p = 0; p < 4; ++p) {
    int f = p * 256 + tid;                           // frag slot = kb*16+row
    int kb = f >> 4, row = f & 15;
    const u16* sp = s_x + row * 520 + kb * 8;
    u16 tmp[8] __attribute__((aligned(16)));
#pragma unroll
    for (int i = 0; i < 8; ++i) tmp[i] = sp[i];
    *reinterpret_cast<uint4*>(dst + (size_t)f * 8) = *reinterpret_cast<const uint4*>(tmp);
  }
}

// Persistent scan. Grid 256: rg = blockIdx&7, cgi = blockIdx>>3.
// W B-fragments live in registers (32 x short8). LDS: h stage 16KB + gate xchg 4KB.
// Waves: 0=r (x pre, h post), 1=z, 2=[poll+stage h, then n_h post], 3=n_x pre.
// h exchange via agent-scope atomics in A-fragment layout; per-wave release flags.
__launch_bounds__(256, 1)
__global__ void scan_kernel(const float* __restrict__ ins,
                            const u16* __restrict__ xpack,   // may be null
                            const float* __restrict__ h0,
                            const float* __restrict__ bi,
                            const float* __restrict__ bhn,
                            const u16* __restrict__ wpack,
                            const float* __restrict__ mask,
                            u16* __restrict__ hbfA,
                            u32* __restrict__ flags,
                            float* __restrict__ out) {
  __shared__ u16  a_lds[64 * 16 * 8];                // staged h, linear frag slots
  __shared__ float o_lds[4 * 256];                   // gate exchange

  const int tid  = threadIdx.x;
  const int rg   = blockIdx.x & 7;
  const int cgi  = blockIdx.x >> 3;
  const int lane = tid & 63;
  const int wv   = tid >> 6;
  const int quad = lane >> 4;
  const int lm   = lane & 15;

  // ---- one-time: W B-fragments -> registers ----
  short8 breg[32];
  {
    const u16* wp = wpack + (size_t)cgi * (128 * 48 * 8);
    if (wv < 2) {
      int n = wv * 16 + lm;                          // r / z gate columns
#pragma unroll
      for (int kk = 0; kk < 32; ++kk) {
        int kb = kk * 4 + quad;
        breg[kk] = *reinterpret_cast<const short8*>(wp + ((size_t)kb * 48 + n) * 8);
      }
    } else {
      int n = 32 + lm;                               // n gate columns
      int kbb = (wv == 2) ? 64 : 0;                  // wv2: h half, wv3: x half
#pragma unroll
      for (int kk = 0; kk < 16; ++kk) {
        int kb = kbb + kk * 4 + quad;
        breg[kk] = *reinterpret_cast<const short8*>(wp + ((size_t)kb * 48 + n) * 8);
      }
    }
  }

  const int b_l = tid >> 4, j_l = tid & 15;
  const int b_g = rg * 16 + b_l;
  const int j_g = cgi * 16 + j_l;
  const float bi_r = bi[j_g], bi_z = bi[512 + j_g], bi_n = bi[1024 + j_g];
  const float bh_nv = bhn[j_g];
  float* ys = out + (size_t)B * H;

  float hprev = h0[b_g * H + j_g];                   // fp32 master state
  float mcur  = mask[b_g];
  const int kb_st = cgi * 2 + (j_l >> 3);            // producer store kb
  u32* hbfA32 = (u32*)hbfA;

  for (int t = 0; t < T; ++t) {
    const int buf = t & 1;
    float mnext = (t < T - 1) ? mask[(t + 1) * B + b_g] : 1.0f;
    f32x4 acc = {0.f, 0.f, 0.f, 0.f};

    if (wv != 2) {
      // ---- x-half MFMAs (overlap peers' publish/propagation) ----
      if (xpack) {
        const u16* xs = xpack + ((size_t)t * 8 + rg) * 8192;
#pragma unroll
        for (int kk = 0; kk < 16; ++kk) {
          int kb = kk * 4 + quad;
          short8 av = *reinterpret_cast<const short8*>(xs + ((size_t)kb * 16 + lm) * 8);
          acc = __builtin_amdgcn_mfma_f32_16x16x32_bf16(av, breg[kk], acc, 0, 0, 0);
        }
      } else {
        const float* xs = ins + ((size_t)t * B + rg * 16 + lm) * D;
#pragma unroll
        for (int kk = 0; kk < 16; ++kk) {
          int kb = kk * 4 + quad;
          float4 f0 = *reinterpret_cast<const float4*>(xs + kb * 8);
          float4 f1 = *reinterpret_cast<const float4*>(xs + kb * 8 + 4);
          u16 tmp[8] __attribute__((aligned(16)));
          tmp[0]=(u16)f2bf(f0.x); tmp[1]=(u16)f2bf(f0.y); tmp[2]=(u16)f2bf(f0.z); tmp[3]=(u16)f2bf(f0.w);
          tmp[4]=(u16)f2bf(f1.x); tmp[5]=(u16)f2bf(f1.y); tmp[6]=(u16)f2bf(f1.z); tmp[7]=(u16)f2bf(f1.w);
          short8 av = *reinterpret_cast<const short8*>(tmp);
          acc = __builtin_amdgcn_mfma_f32_16x16x32_bf16(av, breg[kk], acc, 0, 0, 0);
        }
      }
    } else {
      // ---- wv2: wait for h(t), stage 16KB -> LDS ----
      if (t) {
        const u64* fp = (const u64*)(flags + rg * 128);
        while (true) {
          u64 f = __hip_atomic_load(fp + lane, __ATOMIC_RELAXED, __HIP_MEMORY_SCOPE_AGENT);
          if (__all(((u32)f >= (u32)t) && ((u32)(f >> 32) >= (u32)t))) break;
        }
      }
      const u64* src = (const u64*)(hbfA + ((size_t)buf * 8 + rg) * 8192);
      union HU { u64 d[2]; short8 v; } hu[16];
#pragma unroll
      for (int c = 0; c < 16; ++c) {
        const u64* p = src + c * 128 + lane * 2;     // contiguous 1KB per chunk
        hu[c].d[0] = __hip_atomic_load(p,     __ATOMIC_RELAXED, __HIP_MEMORY_SCOPE_AGENT);
        hu[c].d[1] = __hip_atomic_load(p + 1, __ATOMIC_RELAXED, __HIP_MEMORY_SCOPE_AGENT);
      }
#pragma unroll
      for (int c = 0; c < 16; ++c)
        *reinterpret_cast<short8*>(a_lds + ((size_t)c * 64 + lane) * 8) = hu[c].v;
    }
    __syncthreads();                                 // sync1: stage + o_lds reuse guard

    // ---- h-half MFMAs from LDS (conflict-free ds_read_b128) ----
    if (wv < 2) {
#pragma unroll
      for (int kk = 16; kk < 32; ++kk) {
        int kbh = (kk - 16) * 4 + quad;
        short8 av = *reinterpret_cast<const short8*>(a_lds + ((size_t)kbh * 16 + lm) * 8);
        acc = __builtin_amdgcn_mfma_f32_16x16x32_bf16(av, breg[kk], acc, 0, 0, 0);
      }
    } else if (wv == 2) {
#pragma unroll
      for (int kk = 0; kk < 16; ++kk) {
        int kbh = kk * 4 + quad;
        short8 av = *reinterpret_cast<const short8*>(a_lds + ((size_t)kbh * 16 + lm) * 8);
        acc = __builtin_amdgcn_mfma_f32_16x16x32_bf16(av, breg[kk], acc, 0, 0, 0);
      }
    }
#pragma unroll
    for (int r = 0; r < 4; ++r)                      // C/D: row=quad*4+r, col=lm
      o_lds[wv * 256 + (quad * 4 + r) * 16 + lm] = acc[r];
    __syncthreads();                                 // sync2

    // ---- gate epilogue: thread owns cell (b_g, j_g) ----
    float racc = o_lds[      b_l * 16 + j_l] + bi_r;
    float zacc = o_lds[256 + b_l * 16 + j_l] + bi_z;
    float hnv  = o_lds[512 + b_l * 16 + j_l] + bh_nv;   // wv2 slot = n_h
    float xnv  = o_lds[768 + b_l * 16 + j_l] + bi_n;    // wv3 slot = n_x
    float hp = hprev * mcur;
    float rr = 1.0f / (1.0f + __expf(-racc));
    float zz = 1.0f / (1.0f + __expf(-zacc));
    float s  = xnv + rr * hnv;
    float nn = 1.0f - 2.0f / (1.0f + __expf(2.0f * s));  // tanh(s)
    float hnew = (1.0f - zz) * nn + zz * hp;
    ys[((size_t)t * B + b_g) * H + j_g] = hnew;
    u32 mybf  = f2bf(hnew * mnext);                  // pre-masked for t+1
    u32 other = (u32)__shfl_xor((int)mybf, 1);
    if (!(j_l & 1)) {
      size_t o32 = (((size_t)(1 - buf) * 8 + rg) * 64 + kb_st) * 64 + b_l * 4 + ((j_l & 7) >> 1);
      __hip_atomic_store(hbfA32 + o32, mybf | (other << 16),
                         __ATOMIC_RELAXED, __HIP_MEMORY_SCOPE_AGENT);
    }
    if (t == T - 1) out[b_g * H + j_g] = hnew;
    hprev = hnew; mcur = mnext;
    // per-wave release flag: waits this wave's vmcnt(0), so its h stores are visible
    if (t < T - 1 && lane == 0)
      __hip_atomic_store(flags + rg * 128 + cgi * 4 + wv, (u32)(t + 1),
                         __ATOMIC_RELEASE, __HIP_MEMORY_SCOPE_AGENT);
  }
}

extern "C" void kernel_launch(void* const* d_in, const int* in_sizes, int n_in,
                              void* d_out, int out_size, void* d_ws, size_t ws_size,
                              hipStream_t stream) {
  const float* ins  = (const float*)d_in[0];
  const void*  rst  = d_in[1];
  const float* h0   = (const float*)d_in[2];
  const float* Wi   = (const float*)d_in[3];
  const float* bi   = (const float*)d_in[4];
  const float* Whrz = (const float*)d_in[5];
  const float* Whn  = (const float*)d_in[6];
  const float* bhn  = (const float*)d_in[7];

  char* ws = (char*)d_ws;
  u16*   wpack = (u16*)(ws + WS_WPACK);
  float* mask  = (float*)(ws + WS_MASK);
  u16*   hbfA  = (u16*)(ws + WS_HBFA);
  u32*   flags = (u32*)(ws + WS_FLAGS);
  float* out   = (float*)d_out;

  bool big = ws_size >= WS_XPACK + (size_t)T * B * D * 2;
  const u16* xpack = big ? (const u16*)(ws + WS_XPACK) : nullptr;

  hipLaunchKernelGGL(pack_w_kernel, dim3(768), dim3(256), 0, stream, Wi, Whrz, Whn, wpack);
  hipLaunchKernelGGL(init_kernel, dim3(256), dim3(256), 0, stream, rst, h0, mask, hbfA, flags);
  if (big)
    hipLaunchKernelGGL(convert_x_kernel, dim3(4096), dim3(256), 0, stream,
                       ins, (u16*)(ws + WS_XPACK));

  void* args[10];
  args[0] = (void*)&ins;   args[1] = (void*)&xpack; args[2] = (void*)&h0;
  args[3] = (void*)&bi;    args[4] = (void*)&bhn;   args[5] = (void*)&wpack;
  args[6] = (void*)&mask;  args[7] = (void*)&hbfA;  args[8] = (void*)&flags;
  args[9] = (void*)&out;
  (void)hipLaunchCooperativeKernel((const void*)scan_kernel, dim3(256), dim3(256),
                                   args, 0, stream);
}